// Round 1
// baseline (472.416 us; speedup 1.0000x reference)
//
#include <hip/hip_runtime.h>

typedef __attribute__((ext_vector_type(8))) short short8;
typedef __attribute__((ext_vector_type(4))) short short4v;
typedef __attribute__((ext_vector_type(4))) float f32x4;

#define C_DIM 512
#define S_DIM 4096
#define NCOL 165      // 3 * sum(k=1..10)
#define NCOLP 176     // padded to 11 * 16
#define LDK 40        // padded LDS k-stride (elements): 32 data + 8 pad -> conflict-free b128
#define M_TILE 80     // 16 halo rows + 64 output rows
#define M_OUT 64
#define BK 32
#define NCHUNK 16     // 512 / 32

__device__ __forceinline__ unsigned short f2bf(float f) {
  unsigned u = __builtin_bit_cast(unsigned, f);
  u += 0x7fffu + ((u >> 16) & 1u);          // round-to-nearest-even (no NaN in data)
  return (unsigned short)(u >> 16);
}
__device__ __forceinline__ float bf2f(unsigned short h) {
  unsigned u = ((unsigned)h) << 16;
  return __builtin_bit_cast(float, u);
}

struct WP { const float* w[10]; };

// Pack weights into B^T layout: bt[col][c], col = 3*k(k-1)/2 + t*3 + p, split hi/lo bf16.
__global__ __launch_bounds__(256) void prep_kernel(WP wp, unsigned short* bt_hi,
                                                   unsigned short* bt_lo) {
  int idx = blockIdx.x * 256 + threadIdx.x;   // 176*512 threads exactly
  int col = idx >> 9;
  int c = idx & 511;
  float v = 0.f;
  if (col < NCOL) {
    int kw = 1, base = 0;
    while (col >= base + 3 * kw) { base += 3 * kw; ++kw; }
    int rem = col - base;
    int t = rem / 3, p = rem - 3 * t;
    v = wp.w[kw - 1][(t * C_DIM + c) * 3 + p];   // w_k layout (k, C, P)
  }
  unsigned short hi = f2bf(v);
  unsigned short lo = f2bf(v - bf2f(hi));
  bt_hi[col * C_DIM + c] = hi;
  bt_lo[col * C_DIM + c] = lo;
}

__global__ __launch_bounds__(256, 3) void conv_kernel(const float* __restrict__ x,
                                                      const unsigned short* __restrict__ bt_hi,
                                                      const unsigned short* __restrict__ bt_lo,
                                                      float* __restrict__ out) {
  // LDS: A hi/lo 80*40*2B = 6400 each; B hi/lo 176*40*2B = 14080 each; total 40960.
  // Epilogue reuses the front as 2 slots of 16x176 fp32 Y (22528 B).
  __shared__ __align__(16) unsigned char smem[40960];
  unsigned short* As_hi = (unsigned short*)smem;
  unsigned short* As_lo = (unsigned short*)(smem + 6400);
  unsigned short* Bs_hi = (unsigned short*)(smem + 12800);
  unsigned short* Bs_lo = (unsigned short*)(smem + 26880);
  float* Ys = (float*)smem;

  const int tid = threadIdx.x;
  const int b = blockIdx.x >> 6;        // 64 tiles per batch
  const int tile = blockIdx.x & 63;
  const int s0 = tile * M_OUT;
  const int sBase = s0 - 16;            // halo start
  const int wave = tid >> 6;
  const int lane = tid & 63;
  const int lane15 = lane & 15;
  const int quad = lane >> 4;
  const int n0 = wave * 3;              // n-tile split 3/3/3/2
  const int nmine = (wave < 3) ? 3 : 2;

  f32x4 acc[5][3];
#pragma unroll
  for (int m = 0; m < 5; ++m)
#pragma unroll
    for (int n = 0; n < 3; ++n) acc[m][n] = (f32x4){0.f, 0.f, 0.f, 0.f};

  for (int ch = 0; ch < NCHUNK; ++ch) {
    const int kc = ch * BK;
    // ---- stage A: 80 rows x 32 channels fp32 -> hi/lo bf16 in LDS ----
    for (int idx = tid; idx < 640; idx += 256) {
      int row = idx >> 3;
      int q = idx & 7;
      int s = sBase + row;
      float4 v = make_float4(0.f, 0.f, 0.f, 0.f);
      if (s >= 0) v = *(const float4*)&x[((size_t)(b * S_DIM + s)) * C_DIM + kc + q * 4];
      unsigned short h0 = f2bf(v.x), h1 = f2bf(v.y), h2 = f2bf(v.z), h3 = f2bf(v.w);
      unsigned short l0 = f2bf(v.x - bf2f(h0)), l1 = f2bf(v.y - bf2f(h1));
      unsigned short l2 = f2bf(v.z - bf2f(h2)), l3 = f2bf(v.w - bf2f(h3));
      short4v hv = {(short)h0, (short)h1, (short)h2, (short)h3};
      short4v lv = {(short)l0, (short)l1, (short)l2, (short)l3};
      *(short4v*)&As_hi[row * LDK + q * 4] = hv;
      *(short4v*)&As_lo[row * LDK + q * 4] = lv;
    }
    // ---- stage B: 176 cols x 32 k, hi+lo (L2-resident after first blocks) ----
    for (int idx = tid; idx < 1408; idx += 256) {
      int buf = (idx >= 704) ? 1 : 0;
      int rem = idx - buf * 704;
      int col = rem >> 2;
      int q = rem & 3;
      const unsigned short* src = buf ? bt_lo : bt_hi;
      unsigned short* dst = buf ? Bs_lo : Bs_hi;
      short8 v = *(const short8*)&src[col * C_DIM + kc + q * 8];
      *(short8*)&dst[col * LDK + q * 8] = v;
    }
    __syncthreads();
    // ---- compute: one K=32 MFMA step, 3 products (hi*hi + hi*lo + lo*hi) ----
    short8 bh[3], bl[3];
#pragma unroll
    for (int nn = 0; nn < 3; ++nn) {
      if (nn < nmine) {
        int cr = (n0 + nn) * 16 + lane15;
        bh[nn] = *(const short8*)&Bs_hi[cr * LDK + quad * 8];
        bl[nn] = *(const short8*)&Bs_lo[cr * LDK + quad * 8];
      }
    }
#pragma unroll
    for (int m = 0; m < 5; ++m) {
      int ar = m * 16 + lane15;
      short8 ah = *(const short8*)&As_hi[ar * LDK + quad * 8];
      short8 al = *(const short8*)&As_lo[ar * LDK + quad * 8];
#pragma unroll
      for (int nn = 0; nn < 3; ++nn) {
        if (nn < nmine) {
          acc[m][nn] = __builtin_amdgcn_mfma_f32_16x16x32_bf16(ah, bh[nn], acc[m][nn], 0, 0, 0);
          acc[m][nn] = __builtin_amdgcn_mfma_f32_16x16x32_bf16(ah, bl[nn], acc[m][nn], 0, 0, 0);
          acc[m][nn] = __builtin_amdgcn_mfma_f32_16x16x32_bf16(al, bh[nn], acc[m][nn], 0, 0, 0);
        }
      }
    }
    __syncthreads();
  }

  // ---- epilogue: d-sum + relu via LDS, ping-pong 16x176 Y slots ----
  // C/D layout: col = lane&15 (global col = (n0+nn)*16 + lane15), row = quad*4 + reg.
#pragma unroll
  for (int i = 1; i <= 4; ++i) {
    if (i == 1) {
#pragma unroll
      for (int nn = 0; nn < 3; ++nn)
        if (nn < nmine)
#pragma unroll
          for (int r = 0; r < 4; ++r)
            Ys[0 * 2816 + (quad * 4 + r) * NCOLP + (n0 + nn) * 16 + lane15] = acc[0][nn][r];
    }
#pragma unroll
    for (int nn = 0; nn < 3; ++nn)
      if (nn < nmine)
#pragma unroll
        for (int r = 0; r < 4; ++r)
          Ys[(i & 1) * 2816 + (quad * 4 + r) * NCOLP + (n0 + nn) * 16 + lane15] = acc[i][nn][r];
    __syncthreads();
    for (int o = tid; o < 480; o += 256) {
      int r = o / 30;
      int j = o - 30 * r;
      int kw = j / 3 + 1;
      int p = j - (kw - 1) * 3;
      int base = 3 * (kw * (kw - 1)) / 2;
      float sum = 0.f;
      for (int d = 0; d < kw; ++d) {
        int rr = r - d;
        int slot = (rr >= 0) ? (i & 1) : ((i ^ 1) & 1);
        int lr = (rr >= 0) ? rr : (16 + rr);
        int colv = base + (kw - 1 - d) * 3 + p;
        sum += Ys[slot * 2816 + lr * NCOLP + colv];
      }
      int s = s0 + 16 * (i - 1) + r;
      out[((size_t)(b * S_DIM + s)) * 30 + j] = fmaxf(sum, 0.f);
    }
    __syncthreads();
  }
}

extern "C" void kernel_launch(void* const* d_in, const int* in_sizes, int n_in,
                              void* d_out, int out_size, void* d_ws, size_t ws_size,
                              hipStream_t stream) {
  const float* x = (const float*)d_in[0];
  WP wp;
  for (int k = 0; k < 10; ++k) wp.w[k] = (const float*)d_in[k + 1];
  unsigned short* bt_hi = (unsigned short*)d_ws;
  unsigned short* bt_lo = bt_hi + NCOLP * C_DIM;   // +180224 bytes
  prep_kernel<<<NCOLP * C_DIM / 256, 256, 0, stream>>>(wp, bt_hi, bt_lo);
  conv_kernel<<<32 * (S_DIM / M_OUT), 256, 0, stream>>>(x, bt_hi, bt_lo, (float*)d_out);
}

// Round 2
// 412.803 us; speedup vs baseline: 1.1444x; 1.1444x over previous
//
#include <hip/hip_runtime.h>

typedef __attribute__((ext_vector_type(8))) short short8;
typedef __attribute__((ext_vector_type(4))) float f32x4;

#define C_DIM 512
#define S_DIM 4096
#define NCOL 165      // 3 * sum(k=1..10)
#define NCOLP 176     // padded to 11 * 16
#define LDK 32        // unpadded stride: even bank distribution for b128 frags, DMA-compatible
#define M_TILE 80     // 16 halo rows + 64 output rows
#define M_OUT 64
#define BK 32
#define NCHUNK 16     // 512 / 32

__device__ __forceinline__ unsigned short f2bf(float f) {
  unsigned u = __builtin_bit_cast(unsigned, f);
  u += 0x7fffu + ((u >> 16) & 1u);          // RNE (no NaN in data)
  return (unsigned short)(u >> 16);
}
__device__ __forceinline__ float bf2f(unsigned short h) {
  unsigned u = ((unsigned)h) << 16;
  return __builtin_bit_cast(float, u);
}

struct WP { const float* w[10]; };

// Pack weights into B^T layout: bt[col][c], col = 3*k(k-1)/2 + t*3 + p, split hi/lo bf16.
__global__ __launch_bounds__(256) void prep_kernel(WP wp, unsigned short* bt_hi,
                                                   unsigned short* bt_lo) {
  int idx = blockIdx.x * 256 + threadIdx.x;   // 176*512 threads exactly
  int col = idx >> 9;
  int c = idx & 511;
  float v = 0.f;
  if (col < NCOL) {
    int kw = 1, base = 0;
    while (col >= base + 3 * kw) { base += 3 * kw; ++kw; }
    int rem = col - base;
    int t = rem / 3, p = rem - 3 * t;
    v = wp.w[kw - 1][(t * C_DIM + c) * 3 + p];   // w_k layout (k, C, P)
  }
  unsigned short hi = f2bf(v);
  unsigned short lo = f2bf(v - bf2f(hi));
  bt_hi[col * C_DIM + c] = hi;
  bt_lo[col * C_DIM + c] = lo;
}

__device__ __forceinline__ void gld16(const void* g, void* l) {
  __builtin_amdgcn_global_load_lds(
      (const __attribute__((address_space(1))) unsigned int*)(const unsigned int*)g,
      (__attribute__((address_space(3))) unsigned int*)(unsigned int*)l, 16, 0, 0);
}

// fp32x4 -> packed bf16 hi pair-pair + lo pair-pair, RNE both (identical numerics to v1)
__device__ __forceinline__ void cvt_pack(const float4 v, uint2& hi, uint2& lo) {
  unsigned u0 = __builtin_bit_cast(unsigned, v.x);
  unsigned u1 = __builtin_bit_cast(unsigned, v.y);
  unsigned u2 = __builtin_bit_cast(unsigned, v.z);
  unsigned u3 = __builtin_bit_cast(unsigned, v.w);
  unsigned r0 = u0 + 0x7fffu + ((u0 >> 16) & 1u);
  unsigned r1 = u1 + 0x7fffu + ((u1 >> 16) & 1u);
  unsigned r2 = u2 + 0x7fffu + ((u2 >> 16) & 1u);
  unsigned r3 = u3 + 0x7fffu + ((u3 >> 16) & 1u);
  hi.x = __builtin_amdgcn_perm(r1, r0, 0x07060302u);
  hi.y = __builtin_amdgcn_perm(r3, r2, 0x07060302u);
  float m0 = v.x - __builtin_bit_cast(float, r0 & 0xffff0000u);
  float m1 = v.y - __builtin_bit_cast(float, r1 & 0xffff0000u);
  float m2 = v.z - __builtin_bit_cast(float, r2 & 0xffff0000u);
  float m3 = v.w - __builtin_bit_cast(float, r3 & 0xffff0000u);
  unsigned w0 = __builtin_bit_cast(unsigned, m0); w0 += 0x7fffu + ((w0 >> 16) & 1u);
  unsigned w1 = __builtin_bit_cast(unsigned, m1); w1 += 0x7fffu + ((w1 >> 16) & 1u);
  unsigned w2 = __builtin_bit_cast(unsigned, m2); w2 += 0x7fffu + ((w2 >> 16) & 1u);
  unsigned w3 = __builtin_bit_cast(unsigned, m3); w3 += 0x7fffu + ((w3 >> 16) & 1u);
  lo.x = __builtin_amdgcn_perm(w1, w0, 0x07060302u);
  lo.y = __builtin_amdgcn_perm(w3, w2, 0x07060302u);
}

__global__ __launch_bounds__(256, 4) void conv_kernel(const float* __restrict__ x,
                                                      const unsigned short* __restrict__ bt_hi,
                                                      const unsigned short* __restrict__ bt_lo,
                                                      float* __restrict__ out) {
  // LDS: As hi/lo 80*32*2B = 5120 each; Bs hi/lo 176*32*2B = 11264 each; total 32768.
  // Epilogue reuses front as 2 slots of 16x176 fp32 (22528 B).
  __shared__ __align__(16) unsigned char smem[32768];
  unsigned short* As_hi = (unsigned short*)smem;
  unsigned short* As_lo = (unsigned short*)(smem + 5120);
  unsigned short* Bs_hi = (unsigned short*)(smem + 10240);
  unsigned short* Bs_lo = (unsigned short*)(smem + 21504);
  float* Ys = (float*)smem;

  const int tid = threadIdx.x;
  const int b = blockIdx.x >> 6;        // 64 tiles per batch
  const int tile = blockIdx.x & 63;
  const int s0 = tile * M_OUT;
  const int sBase = s0 - 16;            // halo start
  const int wave = tid >> 6;
  const int lane = tid & 63;
  const int lane15 = lane & 15;
  const int quad = lane >> 4;
  const int n0 = wave * 3;              // n-tile split 3/3/3/2
  const int nmine = (wave < 3) ? 3 : 2;

  // --- per-thread A staging geometry (640 float4 slots over 256 threads: 2.5 each) ---
  const float4* aptr[3];
  bool aexists[3], avalid[3];
  int arow[3], aq[3];
#pragma unroll
  for (int i = 0; i < 3; ++i) {
    int idx = tid + i * 256;
    aexists[i] = (idx < 640);
    arow[i] = idx >> 3;
    aq[i] = idx & 7;
    int s = sBase + arow[i];
    avalid[i] = aexists[i] && (s >= 0);
    aptr[i] = (const float4*)&x[((size_t)(b * S_DIM + (s < 0 ? 0 : s))) * C_DIM + aq[i] * 4];
  }

  float4 pf[3];
  f32x4 acc[5][3];
#pragma unroll
  for (int m = 0; m < 5; ++m)
#pragma unroll
    for (int n = 0; n < 3; ++n) acc[m][n] = (f32x4){0.f, 0.f, 0.f, 0.f};

  // ---------- staging helpers (inlined via lambdas) ----------
  auto loadA = [&](int ch) {
#pragma unroll
    for (int i = 0; i < 3; ++i) {
      if (avalid[i]) pf[i] = aptr[i][ch * 8];          // ch*32 floats = ch*8 float4
      else pf[i] = make_float4(0.f, 0.f, 0.f, 0.f);
    }
  };
  auto cvtWrite = [&]() {
#pragma unroll
    for (int i = 0; i < 3; ++i) {
      if (aexists[i]) {
        uint2 hi, lo;
        cvt_pack(pf[i], hi, lo);
        *(uint2*)&As_hi[arow[i] * LDK + aq[i] * 4] = hi;
        *(uint2*)&As_lo[arow[i] * LDK + aq[i] * 4] = lo;
      }
    }
  };
  auto dmaB = [&](int ch) {
    const int kc = ch * BK;
    for (int j = wave; j < 22; j += 4) {
      int jj = (j < 11) ? j : j - 11;
      const unsigned short* src = (j < 11) ? bt_hi : bt_lo;
      unsigned short* dst = (j < 11) ? Bs_hi : Bs_lo;
      int col = jj * 16 + (lane >> 2);
      int part = lane & 3;
      gld16(src + col * C_DIM + kc + part * 8, dst + jj * 512);
    }
  };

  // ---------- prologue: stage chunk 0 ----------
  loadA(0);
  cvtWrite();
  dmaB(0);
  __syncthreads();

  for (int ch = 0; ch < NCHUNK; ++ch) {
    if (ch < NCHUNK - 1) loadA(ch + 1);   // issue early: latency hides behind MFMA below

    // ---- compute on chunk ch ----
    short8 bh[3], bl[3];
#pragma unroll
    for (int nn = 0; nn < 3; ++nn) {
      if (nn < nmine) {
        int cr = (n0 + nn) * 16 + lane15;
        bh[nn] = *(const short8*)&Bs_hi[cr * LDK + quad * 8];
        bl[nn] = *(const short8*)&Bs_lo[cr * LDK + quad * 8];
      }
    }
#pragma unroll
    for (int m = 0; m < 5; ++m) {
      int ar = m * 16 + lane15;
      short8 ah = *(const short8*)&As_hi[ar * LDK + quad * 8];
      short8 al = *(const short8*)&As_lo[ar * LDK + quad * 8];
#pragma unroll
      for (int nn = 0; nn < 3; ++nn) {
        if (nn < nmine) {
          acc[m][nn] = __builtin_amdgcn_mfma_f32_16x16x32_bf16(ah, bh[nn], acc[m][nn], 0, 0, 0);
          acc[m][nn] = __builtin_amdgcn_mfma_f32_16x16x32_bf16(ah, bl[nn], acc[m][nn], 0, 0, 0);
          acc[m][nn] = __builtin_amdgcn_mfma_f32_16x16x32_bf16(al, bh[nn], acc[m][nn], 0, 0, 0);
        }
      }
    }
    __syncthreads();                       // everyone done reading chunk ch LDS
    if (ch < NCHUNK - 1) {
      cvtWrite();                          // pf -> LDS (loads completed during MFMA)
      dmaB(ch + 1);
      __syncthreads();                     // publish chunk ch+1
    }
  }

  // ---- epilogue: d-sum + relu via LDS, ping-pong 16x176 Y slots ----
  // C/D layout: col = lane&15 (global col = (n0+nn)*16 + lane15), row = quad*4 + reg.
#pragma unroll
  for (int i = 1; i <= 4; ++i) {
    if (i == 1) {
#pragma unroll
      for (int nn = 0; nn < 3; ++nn)
        if (nn < nmine)
#pragma unroll
          for (int r = 0; r < 4; ++r)
            Ys[0 * 2816 + (quad * 4 + r) * NCOLP + (n0 + nn) * 16 + lane15] = acc[0][nn][r];
    }
#pragma unroll
    for (int nn = 0; nn < 3; ++nn)
      if (nn < nmine)
#pragma unroll
        for (int r = 0; r < 4; ++r)
          Ys[(i & 1) * 2816 + (quad * 4 + r) * NCOLP + (n0 + nn) * 16 + lane15] = acc[i][nn][r];
    __syncthreads();
    for (int o = tid; o < 480; o += 256) {
      int r = o / 30;
      int j = o - 30 * r;
      int kw = j / 3 + 1;
      int p = j - (kw - 1) * 3;
      int base = 3 * (kw * (kw - 1)) / 2;
      float sum = 0.f;
      for (int d = 0; d < kw; ++d) {
        int rr = r - d;
        int slot = (rr >= 0) ? (i & 1) : ((i ^ 1) & 1);
        int lr = (rr >= 0) ? rr : (16 + rr);
        int colv = base + (kw - 1 - d) * 3 + p;
        sum += Ys[slot * 2816 + lr * NCOLP + colv];
      }
      int s = s0 + 16 * (i - 1) + r;
      out[((size_t)(b * S_DIM + s)) * 30 + j] = fmaxf(sum, 0.f);
    }
    __syncthreads();
  }
}

extern "C" void kernel_launch(void* const* d_in, const int* in_sizes, int n_in,
                              void* d_out, int out_size, void* d_ws, size_t ws_size,
                              hipStream_t stream) {
  const float* x = (const float*)d_in[0];
  WP wp;
  for (int k = 0; k < 10; ++k) wp.w[k] = (const float*)d_in[k + 1];
  unsigned short* bt_hi = (unsigned short*)d_ws;
  unsigned short* bt_lo = bt_hi + NCOLP * C_DIM;   // +180224 bytes
  prep_kernel<<<NCOLP * C_DIM / 256, 256, 0, stream>>>(wp, bt_hi, bt_lo);
  conv_kernel<<<32 * (S_DIM / M_OUT), 256, 0, stream>>>(x, bt_hi, bt_lo, (float*)d_out);
}